// Round 2
// baseline (244.256 us; speedup 1.0000x reference)
//
#include <hip/hip_runtime.h>
#include <stdint.h>

namespace {
constexpr int kB  = 16384;
constexpr int kN  = 128;
constexpr int kI  = 3;
constexpr int kC  = 4;
constexpr int kH  = 90;
constexpr int kL  = 3;
constexpr int BT  = 64;     // batch rows per block (1 wave, 2 nt tiles of 32)
constexpr int KP  = 96;
// 32x32x16 A-frag image: per node 57 frag-blocks of 1024 B:
//   fb 0-2   : layer0  (mt 0..2, single ks, K=16 with k>=8 zero)
//   fb 3+l*18+ks*3+mt : hidden layer l, ks 0..5, mt 0..2
constexpr int FB_PER_NODE = 57;
constexpr int NODE_USH    = FB_PER_NODE * 512;                 // 29184
constexpr size_t WT_BYTES = (size_t)kN * NODE_USH * 2;         // 7,471,104
constexpr size_t WO_OFF   = WT_BYTES;                          // float wo[128][96]
constexpr size_t XK_OFF   = WO_OFF + (size_t)kN * KP * 4;      // ushort xk[384][16384]
constexpr size_t OT_OFF   = XK_OFF + (size_t)kN * kI * kB * 2; // float outT[128][16384]
}

typedef __attribute__((ext_vector_type(8))) short bf16x8;
typedef __attribute__((ext_vector_type(4))) float f32x4;
typedef __attribute__((ext_vector_type(16))) float f32x16;

__device__ __forceinline__ uint32_t pack_bf16(float lo, float hi) {
#if __has_builtin(__builtin_amdgcn_cvt_pk_bf16_f32)
  auto r = __builtin_amdgcn_cvt_pk_bf16_f32(lo, hi);
  union { decltype(r) v; uint32_t u; } c; c.v = r; return c.u;
#else
  union { float f; uint32_t i; } a, b; a.f = lo; b.f = hi;
  uint32_t ua = a.i + 0x8000u;
  uint32_t ub = b.i + 0x8000u;
  return __builtin_amdgcn_perm(ub, ua, 0x07060302);
#endif
}
__device__ __forceinline__ ushort f2bf(float f) {
  union { float f; uint32_t i; } v; v.f = f;
  uint32_t u = v.i + 0x7FFFu + ((v.i >> 16) & 1u);
  return (ushort)(u >> 16);
}

// half-wave exchange: a' = [lanes0-31: a | lanes32-63: b(lanes0-31)],
//                     b' = [lanes0-31: a(lanes32-63) | lanes32-63: b]
__device__ __forceinline__ void pl32swap(uint32_t& a, uint32_t& b) {
#if __has_builtin(__builtin_amdgcn_permlane32_swap)
  auto r = __builtin_amdgcn_permlane32_swap(a, b, false, false);
  a = (uint32_t)r[0]; b = (uint32_t)r[1];
#else
  uint32_t sa = (uint32_t)__shfl_xor((int)a, 32);
  uint32_t sb = (uint32_t)__shfl_xor((int)b, 32);
  bool lo = (threadIdx.x & 63) < 32;
  uint32_t na = lo ? a : sb;
  uint32_t nb = lo ? sa : b;
  a = na; b = nb;
#endif
}

// ---- merged preprocess: 32x32x16 A-frag weight image + wo + x transpose ----
__global__ __launch_bounds__(256) void prep_kernel(
    const float* __restrict__ x,
    const float* __restrict__ W_in, const float* __restrict__ b_in,
    const float* __restrict__ W_hid, const float* __restrict__ b_hid,
    const float* __restrict__ W_out, const float* __restrict__ b_out,
    ushort* __restrict__ wt, float* __restrict__ wo, ushort* __restrict__ xk)
{
  __shared__ float smem[kH * (kH + 1) + kH];
  const int tid = threadIdx.x;
  const int bid = blockIdx.x;

  if (bid < 4 * kN) {          // ---- weight tiles, A-frag-contiguous ----
    float* ldsw = smem;                      // [k][j], stride kH+1 = 91
    float* ldsb = smem + kH * (kH + 1);
    const int node  = bid & (kN - 1);
    const int layer = bid >> 7;
    const int ksrc  = (layer == 0) ? (kI + kC) : kH;
    const float* src;
    const float* bsrc;
    if (layer == 0) { src = W_in + (size_t)node * (kI + kC) * kH; bsrc = b_in + (size_t)node * kH; }
    else {
      int l = layer - 1;
      src  = W_hid + (size_t)(l * kN + node) * kH * kH;
      bsrc = b_hid + (size_t)(l * kN + node) * kH;
    }
    for (int idx = tid; idx < ksrc * kH; idx += 256)
      ldsw[(idx / kH) * (kH + 1) + (idx % kH)] = src[idx];
    if (tid < kH) ldsb[tid] = bsrc[tid];
    __syncthreads();
    ushort* dstbase = wt + (size_t)node * NODE_USH
                    + (size_t)((layer == 0) ? 0 : 3 + (layer - 1) * 18) * 512;
    const int nch = (layer == 0) ? 192 : 1152;   // 16B chunks (fb*64 + lane)
#pragma unroll
    for (int it = 0; it < 5; ++it) {
      int c = tid + it * 256;
      if (c < nch) {
        int fb = c >> 6, lane = c & 63;
        int ks = (layer == 0) ? 0 : fb / 3;
        int mt = (layer == 0) ? fb : fb % 3;
        int j  = mt * 32 + (lane & 31);
        int kb = ks * 16 + (lane >> 5) * 8;
        float v[8];
#pragma unroll
        for (int i = 0; i < 8; ++i) {
          int k = kb + i;
          float t = 0.f;
          if (j < kH) {
            if (k < ksrc)       t = ldsw[k * (kH + 1) + j];
            else if (k == ksrc) t = ldsb[j];
          }
          v[i] = t;
        }
        uint4 p;
        p.x = pack_bf16(v[0], v[1]); p.y = pack_bf16(v[2], v[3]);
        p.z = pack_bf16(v[4], v[5]); p.w = pack_bf16(v[6], v[7]);
        *(uint4*)&dstbase[(size_t)c * 8] = p;
      }
    }
  } else if (bid < 4 * kN + 4) {   // ---- wout float image (j=90 -> b_out) ----
    int base = (bid - 4 * kN) * 3072;
    for (int t = 0; t < 12; ++t) {
      int idx = base + t * 256 + tid;
      int node = idx / KP, j = idx % KP;
      float v = 0.f;
      if (j < kH)       v = W_out[node * kH + j];
      else if (j == kH) v = b_out[node];
      wo[idx] = v;
    }
  } else {                         // ---- x transpose -> xk[384][16384] bf16 ----
    int xb = bid - (4 * kN + 4);
    int b0 = (xb & 255) * 64;
    int c0 = (xb >> 8) * 96;
    float* lds = smem;             // [64][97]
    for (int idx = tid; idx < 64 * 96; idx += 256) {
      int r = idx / 96, c = idx % 96;
      lds[r * 97 + c] = x[(size_t)(b0 + r) * (kN * kI) + c0 + c];
    }
    __syncthreads();
#pragma unroll
    for (int it = 0; it < 3; ++it) {            // 96 rows x 8 chunks = 768
      int c = tid + it * 256;
      int nk = c >> 3, b = (c & 7) * 8;
      float v[8];
#pragma unroll
      for (int i = 0; i < 8; ++i) v[i] = lds[(b + i) * 97 + nk];
      uint4 p;
      p.x = pack_bf16(v[0], v[1]); p.y = pack_bf16(v[2], v[3]);
      p.z = pack_bf16(v[4], v[5]); p.w = pack_bf16(v[6], v[7]);
      *(uint4*)&xk[(size_t)(c0 + nk) * kB + b0 + b] = p;
    }
  }
}

// ---- main: 32x32x16 MFMA, zero LDS, register-only h redistribution.
// acc D-layout: row=(r&3)+8*(r>>2)+4*hh, col=lane&31.
// Next-layer B-frag (k=(lane>>5)*8+i, col=lane&31) built by packing acc
// reg-pairs to bf16 and permlane32_swap: swap(P0,P2)->(w0,w2) of ks even,
// swap(P1,P3)->(w1,w3); swap(P4,P6)/(P5,P7) -> ks odd. 4 swaps per 16 vals.
__global__ __launch_bounds__(64, 3) void dnpu_kernel(
    const ushort* __restrict__ xk, const float* __restrict__ controls,
    const ushort* __restrict__ wt, const float* __restrict__ wo,
    float* __restrict__ outT)
{
  const int lane = threadIdx.x;
  const int node = (int)(blockIdx.x & 127);
  const int m0   = (int)(blockIdx.x >> 7) * BT;
  const int col  = lane & 31;
  const int hh   = lane >> 5;

  const f32x16 zf = (f32x16)0.0f;
  f32x16 acc[3][2];

  // ---- layer0 B-frags: k = 8*hh + i -> h1 half is the K-pad (zeros) ----
  bf16x8 b0[2];
  {
    const ushort cb0 = f2bf(controls[node * kC + 0]);
    const ushort cb1 = f2bf(controls[node * kC + 1]);
    const ushort cb2 = f2bf(controls[node * kC + 2]);
    const ushort cb3 = f2bf(controls[node * kC + 3]);
    const ushort* xp = xk + (size_t)node * kI * kB + m0 + col;
#pragma unroll
    for (int nt = 0; nt < 2; ++nt) {
      union { ushort s[8]; bf16x8 v; } f;
      f.s[0] = xp[0 * kB + nt * 32];
      f.s[1] = xp[1 * kB + nt * 32];
      f.s[2] = xp[2 * kB + nt * 32];
      f.s[3] = cb0; f.s[4] = cb1; f.s[5] = cb2; f.s[6] = cb3;
      f.s[7] = 0x3F80;                       // 1.0 (bias row k=7)
      bf16x8 z = (bf16x8){0,0,0,0,0,0,0,0};
      if (hh) b0[nt] = z; else b0[nt] = f.v;
    }
  }

  // ---- layer0 gemm ----
  {
    const ushort* t0 = wt + (size_t)node * NODE_USH;
#pragma unroll
    for (int mt = 0; mt < 3; ++mt) {
      bf16x8 afr = *(const bf16x8*)&t0[mt * 512 + lane * 8];
#pragma unroll
      for (int nt = 0; nt < 2; ++nt)
        acc[mt][nt] = __builtin_amdgcn_mfma_f32_32x32x16_bf16(afr, b0[nt], zf, 0, 0, 0);
    }
  }

  union BF { uint32_t u[4]; bf16x8 v; };
  BF Bw[6][2];

  // relu+pack acc -> B-frags for all 6 ks of the next gemm (registers only).
  // j=90 bias channel: acc[2], h0, reg14 := 1.0 (lands in ks=5, h1, i=2).
  auto packB = [&]() {
#pragma unroll
    for (int mt = 0; mt < 3; ++mt)
#pragma unroll
      for (int nt = 0; nt < 2; ++nt) {
        float v[16];
#pragma unroll
        for (int r = 0; r < 16; ++r) v[r] = fmaxf(acc[mt][nt][r], 0.f);
        if (mt == 2) v[14] = (hh == 0) ? 1.0f : v[14];
        uint32_t P[8];
#pragma unroll
        for (int w = 0; w < 8; ++w) P[w] = pack_bf16(v[2 * w], v[2 * w + 1]);
        uint32_t a0 = P[0], c0 = P[2]; pl32swap(a0, c0);
        uint32_t a1 = P[1], c1 = P[3]; pl32swap(a1, c1);
        uint32_t a2 = P[4], c2 = P[6]; pl32swap(a2, c2);
        uint32_t a3 = P[5], c3 = P[7]; pl32swap(a3, c3);
        Bw[2 * mt][nt].u[0] = a0; Bw[2 * mt][nt].u[1] = a1;
        Bw[2 * mt][nt].u[2] = c0; Bw[2 * mt][nt].u[3] = c1;
        Bw[2 * mt + 1][nt].u[0] = a2; Bw[2 * mt + 1][nt].u[1] = a3;
        Bw[2 * mt + 1][nt].u[2] = c2; Bw[2 * mt + 1][nt].u[3] = c3;
      }
  };

#pragma unroll
  for (int l = 0; l < kL; ++l) {
    packB();
    const ushort* tl = wt + (size_t)node * NODE_USH + (size_t)(3 + l * 18) * 512;
#pragma unroll
    for (int ks = 0; ks < 6; ++ks)
#pragma unroll
      for (int mt = 0; mt < 3; ++mt) {
        bf16x8 afr = *(const bf16x8*)&tl[(size_t)(ks * 3 + mt) * 512 + lane * 8];
#pragma unroll
        for (int nt = 0; nt < 2; ++nt)
          acc[mt][nt] = __builtin_amdgcn_mfma_f32_32x32x16_bf16(
              afr, Bw[ks][nt].v, (ks == 0) ? zf : acc[mt][nt], 0, 0, 0);
      }
  }

  // ---- final dot: out = relu(h3) . wout (+ b_out via j=90) ----
  {
    const float* wop = wo + node * KP;
    float s0 = 0.f, s1 = 0.f;
#pragma unroll
    for (int mt = 0; mt < 3; ++mt) {
#pragma unroll
      for (int g = 0; g < 4; ++g) {
        // lane (hh) covers rows j = mt*32 + 8g + 4*hh + r2
        float4 wf = *(const float4*)&wop[mt * 32 + g * 8 + hh * 4];
#pragma unroll
        for (int r2 = 0; r2 < 4; ++r2) {
          int r = g * 4 + r2;
          float w = (r2 == 0) ? wf.x : (r2 == 1) ? wf.y : (r2 == 2) ? wf.z : wf.w;
          float h0v = fmaxf(acc[mt][0][r], 0.f);
          float h1v = fmaxf(acc[mt][1][r], 0.f);
          if (mt == 2 && r == 14) {          // j=90 (h0): 1.0 pairs with wo[90]=b_out
            h0v = (hh == 0) ? 1.0f : h0v;
            h1v = (hh == 0) ? 1.0f : h1v;
          }
          s0 += h0v * w; s1 += h1v * w;
        }
      }
    }
    s0 += __shfl_xor(s0, 32);
    s1 += __shfl_xor(s1, 32);
    float r = hh ? s1 : s0;                  // lane l -> batch m0 + l
    outT[(size_t)node * kB + m0 + lane] = r;
  }
}

// ---- outT [128][16384] -> out [16384][128], LDS-tiled, coalesced both sides ----
__global__ __launch_bounds__(256) void transpose_out(
    const float* __restrict__ ot, float* __restrict__ out)
{
  __shared__ float t[64][65];
  const int b0 = (int)(blockIdx.x & 255) * 64;
  const int n0 = (int)(blockIdx.x >> 8) * 64;
  const int c  = threadIdx.x & 63;
  const int r4 = threadIdx.x >> 6;
#pragma unroll
  for (int i = 0; i < 16; ++i) {
    int n = r4 + i * 4;
    t[n][c] = ot[(size_t)(n0 + n) * kB + b0 + c];
  }
  __syncthreads();
#pragma unroll
  for (int i = 0; i < 16; ++i) {
    int b = r4 + i * 4;
    out[(size_t)(b0 + b) * kN + n0 + c] = t[c][b];
  }
}

extern "C" void kernel_launch(void* const* d_in, const int* in_sizes, int n_in,
                              void* d_out, int out_size, void* d_ws, size_t ws_size,
                              hipStream_t stream) {
  const float* x        = (const float*)d_in[0];
  const float* controls = (const float*)d_in[1];
  const float* W_in     = (const float*)d_in[2];
  const float* b_in     = (const float*)d_in[3];
  const float* W_hid    = (const float*)d_in[4];
  const float* b_hid    = (const float*)d_in[5];
  const float* W_out    = (const float*)d_in[6];
  const float* b_out    = (const float*)d_in[7];
  float* out = (float*)d_out;

  ushort* wt = (ushort*)d_ws;
  float*  wo = (float*)((char*)d_ws + WO_OFF);
  ushort* xk = (ushort*)((char*)d_ws + XK_OFF);
  float*  ot = (float*)((char*)d_ws + OT_OFF);

  hipLaunchKernelGGL(prep_kernel, dim3(4 * kN + 4 + 1024), dim3(256), 0, stream,
                     x, W_in, b_in, W_hid, b_hid, W_out, b_out, wt, wo, xk);

  dim3 grid((kB / BT) * kN);   // bid = tile*128 + node -> node fixed per CU
  hipLaunchKernelGGL(dnpu_kernel, grid, dim3(64), 0, stream,
                     xk, controls, wt, wo, ot);

  hipLaunchKernelGGL(transpose_out, dim3(512), dim3(256), 0, stream, ot, out);
}

// Round 3
// 219.660 us; speedup vs baseline: 1.1120x; 1.1120x over previous
//
#include <hip/hip_runtime.h>
#include <stdint.h>

namespace {
constexpr int kB  = 16384;
constexpr int kN  = 128;
constexpr int kI  = 3;
constexpr int kC  = 4;
constexpr int kH  = 90;
constexpr int kL  = 3;
constexpr int KP  = 96;
// 32x32x16 A-frag image: per node 57 frag-blocks of 1024 B:
//   fb 0-2   : layer0  (mt 0..2, single ks, K=16 with k>=8 zero)
//   fb 3+l*18+ks*3+mt : hidden layer l, ks 0..5, mt 0..2
constexpr int FB_PER_NODE = 57;
constexpr int NODE_USH    = FB_PER_NODE * 512;                 // 29184
constexpr size_t WT_BYTES = (size_t)kN * NODE_USH * 2;         // 7,471,104
constexpr size_t WO_OFF   = WT_BYTES;                          // float wo[128][96]
constexpr size_t XK_OFF   = WO_OFF + (size_t)kN * KP * 4;      // ushort xk[384][16384]
constexpr size_t OT_OFF   = XK_OFF + (size_t)kN * kI * kB * 2; // float outT[128][16384]
}

typedef __attribute__((ext_vector_type(8))) short bf16x8;
typedef __attribute__((ext_vector_type(4))) float f32x4;
typedef __attribute__((ext_vector_type(16))) float f32x16;

__device__ __forceinline__ uint32_t pack_bf16(float lo, float hi) {
#if __has_builtin(__builtin_amdgcn_cvt_pk_bf16_f32)
  auto r = __builtin_amdgcn_cvt_pk_bf16_f32(lo, hi);
  union { decltype(r) v; uint32_t u; } c; c.v = r; return c.u;
#else
  union { float f; uint32_t i; } a, b; a.f = lo; b.f = hi;
  uint32_t ua = a.i + 0x8000u;
  uint32_t ub = b.i + 0x8000u;
  return __builtin_amdgcn_perm(ub, ua, 0x07060302);
#endif
}
__device__ __forceinline__ ushort f2bf(float f) {
  union { float f; uint32_t i; } v; v.f = f;
  uint32_t u = v.i + 0x7FFFu + ((v.i >> 16) & 1u);
  return (ushort)(u >> 16);
}

// half-wave exchange (see r2 derivation; verified by passing refcheck)
__device__ __forceinline__ void pl32swap(uint32_t& a, uint32_t& b) {
#if __has_builtin(__builtin_amdgcn_permlane32_swap)
  auto r = __builtin_amdgcn_permlane32_swap(a, b, false, false);
  a = (uint32_t)r[0]; b = (uint32_t)r[1];
#else
  uint32_t sa = (uint32_t)__shfl_xor((int)a, 32);
  uint32_t sb = (uint32_t)__shfl_xor((int)b, 32);
  bool lo = (threadIdx.x & 63) < 32;
  uint32_t na = lo ? a : sb;
  uint32_t nb = lo ? sa : b;
  a = na; b = nb;
#endif
}

// async global->LDS, 16B per lane; LDS dest must be wave-uniform base.
__device__ __forceinline__ void stage16(const ushort* g, ushort* l) {
  __builtin_amdgcn_global_load_lds(
      (const __attribute__((address_space(1))) void*)g,
      (__attribute__((address_space(3))) void*)l, 16, 0, 0);
}

// ---- merged preprocess: 32x32x16 A-frag weight image + wo + x transpose ----
__global__ __launch_bounds__(256) void prep_kernel(
    const float* __restrict__ x,
    const float* __restrict__ W_in, const float* __restrict__ b_in,
    const float* __restrict__ W_hid, const float* __restrict__ b_hid,
    const float* __restrict__ W_out, const float* __restrict__ b_out,
    ushort* __restrict__ wt, float* __restrict__ wo, ushort* __restrict__ xk)
{
  __shared__ float smem[kH * (kH + 1) + kH];
  const int tid = threadIdx.x;
  const int bid = blockIdx.x;

  if (bid < 4 * kN) {          // ---- weight tiles, A-frag-contiguous ----
    float* ldsw = smem;                      // [k][j], stride kH+1 = 91
    float* ldsb = smem + kH * (kH + 1);
    const int node  = bid & (kN - 1);
    const int layer = bid >> 7;
    const int ksrc  = (layer == 0) ? (kI + kC) : kH;
    const float* src;
    const float* bsrc;
    if (layer == 0) { src = W_in + (size_t)node * (kI + kC) * kH; bsrc = b_in + (size_t)node * kH; }
    else {
      int l = layer - 1;
      src  = W_hid + (size_t)(l * kN + node) * kH * kH;
      bsrc = b_hid + (size_t)(l * kN + node) * kH;
    }
    for (int idx = tid; idx < ksrc * kH; idx += 256)
      ldsw[(idx / kH) * (kH + 1) + (idx % kH)] = src[idx];
    if (tid < kH) ldsb[tid] = bsrc[tid];
    __syncthreads();
    ushort* dstbase = wt + (size_t)node * NODE_USH
                    + (size_t)((layer == 0) ? 0 : 3 + (layer - 1) * 18) * 512;
    const int nch = (layer == 0) ? 192 : 1152;   // 16B chunks (fb*64 + lane)
#pragma unroll
    for (int it = 0; it < 5; ++it) {
      int c = tid + it * 256;
      if (c < nch) {
        int fb = c >> 6, lane = c & 63;
        int ks = (layer == 0) ? 0 : fb / 3;
        int mt = (layer == 0) ? fb : fb % 3;
        int j  = mt * 32 + (lane & 31);
        int kb = ks * 16 + (lane >> 5) * 8;
        float v[8];
#pragma unroll
        for (int i = 0; i < 8; ++i) {
          int k = kb + i;
          float t = 0.f;
          if (j < kH) {
            if (k < ksrc)       t = ldsw[k * (kH + 1) + j];
            else if (k == ksrc) t = ldsb[j];
          }
          v[i] = t;
        }
        uint4 p;
        p.x = pack_bf16(v[0], v[1]); p.y = pack_bf16(v[2], v[3]);
        p.z = pack_bf16(v[4], v[5]); p.w = pack_bf16(v[6], v[7]);
        *(uint4*)&dstbase[(size_t)c * 8] = p;
      }
    }
  } else if (bid < 4 * kN + 4) {   // ---- wout float image (j=90 -> b_out) ----
    int base = (bid - 4 * kN) * 3072;
    for (int t = 0; t < 12; ++t) {
      int idx = base + t * 256 + tid;
      int node = idx / KP, j = idx % KP;
      float v = 0.f;
      if (j < kH)       v = W_out[node * kH + j];
      else if (j == kH) v = b_out[node];
      wo[idx] = v;
    }
  } else {                         // ---- x transpose -> xk[384][16384] bf16 ----
    int xb = bid - (4 * kN + 4);
    int b0 = (xb & 255) * 64;
    int c0 = (xb >> 8) * 96;
    float* lds = smem;             // [64][97]
    for (int idx = tid; idx < 64 * 96; idx += 256) {
      int r = idx / 96, c = idx % 96;
      lds[r * 97 + c] = x[(size_t)(b0 + r) * (kN * kI) + c0 + c];
    }
    __syncthreads();
#pragma unroll
    for (int it = 0; it < 3; ++it) {            // 96 rows x 8 chunks = 768
      int c = tid + it * 256;
      int nk = c >> 3, b = (c & 7) * 8;
      float v[8];
#pragma unroll
      for (int i = 0; i < 8; ++i) v[i] = lds[(b + i) * 97 + nk];
      uint4 p;
      p.x = pack_bf16(v[0], v[1]); p.y = pack_bf16(v[2], v[3]);
      p.z = pack_bf16(v[4], v[5]); p.w = pack_bf16(v[6], v[7]);
      *(uint4*)&xk[(size_t)(c0 + nk) * kB + b0 + b] = p;
    }
  }
}

// ---- main: 32x32x16 MFMA, register-only h redistribution (r2, kept),
// + LDS-staged double-buffered weight tiles via global_load_lds (new).
// 4-wave blocks share one node's tile: stage issue amortized 4x, inner
// loop reads become ds_read_b128 (~12cyc) instead of global (~200cyc).
__global__ __launch_bounds__(256, 3) void dnpu_kernel(
    const ushort* __restrict__ xk, const float* __restrict__ controls,
    const ushort* __restrict__ wt, const float* __restrict__ wo,
    float* __restrict__ outT)
{
  __shared__ __align__(16) ushort wbuf[2][18 * 512];   // 2 x 18,432 B

  const int tid  = threadIdx.x;
  const int lane = tid & 63;
  const int wid  = tid >> 6;
  const int node = (int)(blockIdx.x & 127);
  const int m0   = (int)(blockIdx.x >> 7) * 256 + wid * 64;
  const int col  = lane & 31;
  const int hh   = lane >> 5;

  const ushort* wnode = wt + (size_t)node * NODE_USH;

  // stage a hidden layer's 18KB tile (1152 x 16B chunks) into buf
  auto stage_hid = [&](int l, ushort* buf) {
    const ushort* src = wnode + (size_t)(3 + l * 18) * 512;
#pragma unroll
    for (int r = 0; r < 4; ++r)
      stage16(src + (size_t)(r * 256 + wid * 64 + lane) * 8,
              buf + (size_t)(r * 256 + wid * 64) * 8);
    if (wid < 2)
      stage16(src + (size_t)(1024 + wid * 64 + lane) * 8,
              buf + (size_t)(1024 + wid * 64) * 8);
  };

  // issue: L0 (3 fb) -> wbuf[0], H1 -> wbuf[1]
  if (wid < 3)
    stage16(wnode + (size_t)(wid * 64 + lane) * 8, &wbuf[0][(size_t)(wid * 64) * 8]);
  stage_hid(0, &wbuf[1][0]);

  const f32x16 zf = (f32x16)0.0f;
  f32x16 acc[3][2];

  // ---- layer0 B-frags (overlaps stage latency) ----
  bf16x8 b0[2];
  {
    const ushort cb0 = f2bf(controls[node * kC + 0]);
    const ushort cb1 = f2bf(controls[node * kC + 1]);
    const ushort cb2 = f2bf(controls[node * kC + 2]);
    const ushort cb3 = f2bf(controls[node * kC + 3]);
    const ushort* xp = xk + (size_t)node * kI * kB + m0 + col;
#pragma unroll
    for (int nt = 0; nt < 2; ++nt) {
      union { ushort s[8]; bf16x8 v; } f;
      f.s[0] = xp[0 * kB + nt * 32];
      f.s[1] = xp[1 * kB + nt * 32];
      f.s[2] = xp[2 * kB + nt * 32];
      f.s[3] = cb0; f.s[4] = cb1; f.s[5] = cb2; f.s[6] = cb3;
      f.s[7] = 0x3F80;                       // 1.0 (bias row k=7)
      bf16x8 z = (bf16x8){0,0,0,0,0,0,0,0};
      if (hh) b0[nt] = z; else b0[nt] = f.v;
    }
  }

  union BF { uint32_t u[4]; bf16x8 v; };
  BF Bw[6][2];

  // relu+pack acc -> B-frags for next gemm (registers only, r2-verified).
  auto packB = [&]() {
#pragma unroll
    for (int mt = 0; mt < 3; ++mt)
#pragma unroll
      for (int nt = 0; nt < 2; ++nt) {
        float v[16];
#pragma unroll
        for (int r = 0; r < 16; ++r) v[r] = fmaxf(acc[mt][nt][r], 0.f);
        if (mt == 2) v[14] = (hh == 0) ? 1.0f : v[14];
        uint32_t P[8];
#pragma unroll
        for (int w = 0; w < 8; ++w) P[w] = pack_bf16(v[2 * w], v[2 * w + 1]);
        uint32_t a0 = P[0], c0 = P[2]; pl32swap(a0, c0);
        uint32_t a1 = P[1], c1 = P[3]; pl32swap(a1, c1);
        uint32_t a2 = P[4], c2 = P[6]; pl32swap(a2, c2);
        uint32_t a3 = P[5], c3 = P[7]; pl32swap(a3, c3);
        Bw[2 * mt][nt].u[0] = a0; Bw[2 * mt][nt].u[1] = a1;
        Bw[2 * mt][nt].u[2] = c0; Bw[2 * mt][nt].u[3] = c1;
        Bw[2 * mt + 1][nt].u[0] = a2; Bw[2 * mt + 1][nt].u[1] = a3;
        Bw[2 * mt + 1][nt].u[2] = c2; Bw[2 * mt + 1][nt].u[3] = c3;
      }
  };

  auto compute_hidden = [&](const ushort* buf) {
    __builtin_amdgcn_s_setprio(1);
#pragma unroll
    for (int ks = 0; ks < 6; ++ks)
#pragma unroll
      for (int mt = 0; mt < 3; ++mt) {
        bf16x8 afr = *(const bf16x8*)&buf[(size_t)(ks * 3 + mt) * 512 + lane * 8];
#pragma unroll
        for (int nt = 0; nt < 2; ++nt)
          acc[mt][nt] = __builtin_amdgcn_mfma_f32_32x32x16_bf16(
              afr, Bw[ks][nt].v, (ks == 0) ? zf : acc[mt][nt], 0, 0, 0);
      }
    __builtin_amdgcn_s_setprio(0);
  };

  __syncthreads();                 // vmcnt(0)+barrier: L0, H1 staged

  // ---- layer0 gemm from LDS ----
  {
    __builtin_amdgcn_s_setprio(1);
#pragma unroll
    for (int mt = 0; mt < 3; ++mt) {
      bf16x8 afr = *(const bf16x8*)&wbuf[0][(size_t)mt * 512 + lane * 8];
#pragma unroll
      for (int nt = 0; nt < 2; ++nt)
        acc[mt][nt] = __builtin_amdgcn_mfma_f32_32x32x16_bf16(afr, b0[nt], zf, 0, 0, 0);
    }
    __builtin_amdgcn_s_setprio(0);
  }

  // ---- hidden layers, double-buffered ----
  packB();
  __syncthreads();                 // all waves done reading wbuf[0]
  stage_hid(1, &wbuf[0][0]);       // H2 -> A (flies under H1 compute)
  compute_hidden(&wbuf[1][0]);     // H1

  packB();
  __syncthreads();                 // H2 ready; all done reading wbuf[1]
  stage_hid(2, &wbuf[1][0]);       // H3 -> B (flies under H2 compute)
  compute_hidden(&wbuf[0][0]);     // H2

  packB();
  __syncthreads();                 // H3 ready
  compute_hidden(&wbuf[1][0]);     // H3

  // ---- final dot: out = relu(h3) . wout (+ b_out via j=90) ----
  {
    const float* wop = wo + node * KP;
    float s0 = 0.f, s1 = 0.f;
#pragma unroll
    for (int mt = 0; mt < 3; ++mt) {
#pragma unroll
      for (int g = 0; g < 4; ++g) {
        // lane (hh) covers rows j = mt*32 + 8g + 4*hh + r2
        float4 wf = *(const float4*)&wop[mt * 32 + g * 8 + hh * 4];
#pragma unroll
        for (int r2 = 0; r2 < 4; ++r2) {
          int r = g * 4 + r2;
          float w = (r2 == 0) ? wf.x : (r2 == 1) ? wf.y : (r2 == 2) ? wf.z : wf.w;
          float h0v = fmaxf(acc[mt][0][r], 0.f);
          float h1v = fmaxf(acc[mt][1][r], 0.f);
          if (mt == 2 && r == 14) {          // j=90 (h0): 1.0 pairs with wo[90]=b_out
            h0v = (hh == 0) ? 1.0f : h0v;
            h1v = (hh == 0) ? 1.0f : h1v;
          }
          s0 += h0v * w; s1 += h1v * w;
        }
      }
    }
    s0 += __shfl_xor(s0, 32);
    s1 += __shfl_xor(s1, 32);
    float r = hh ? s1 : s0;                  // lane l -> batch m0 + l
    outT[(size_t)node * kB + m0 + lane] = r;
  }
}

// ---- outT [128][16384] -> out [16384][128], LDS-tiled, coalesced both sides ----
__global__ __launch_bounds__(256) void transpose_out(
    const float* __restrict__ ot, float* __restrict__ out)
{
  __shared__ float t[64][65];
  const int b0 = (int)(blockIdx.x & 255) * 64;
  const int n0 = (int)(blockIdx.x >> 8) * 64;
  const int c  = threadIdx.x & 63;
  const int r4 = threadIdx.x >> 6;
#pragma unroll
  for (int i = 0; i < 16; ++i) {
    int n = r4 + i * 4;
    t[n][c] = ot[(size_t)(n0 + n) * kB + b0 + c];
  }
  __syncthreads();
#pragma unroll
  for (int i = 0; i < 16; ++i) {
    int b = r4 + i * 4;
    out[(size_t)(b0 + b) * kN + n0 + c] = t[c][b];
  }
}

extern "C" void kernel_launch(void* const* d_in, const int* in_sizes, int n_in,
                              void* d_out, int out_size, void* d_ws, size_t ws_size,
                              hipStream_t stream) {
  const float* x        = (const float*)d_in[0];
  const float* controls = (const float*)d_in[1];
  const float* W_in     = (const float*)d_in[2];
  const float* b_in     = (const float*)d_in[3];
  const float* W_hid    = (const float*)d_in[4];
  const float* b_hid    = (const float*)d_in[5];
  const float* W_out    = (const float*)d_in[6];
  const float* b_out    = (const float*)d_in[7];
  float* out = (float*)d_out;

  ushort* wt = (ushort*)d_ws;
  float*  wo = (float*)((char*)d_ws + WO_OFF);
  ushort* xk = (ushort*)((char*)d_ws + XK_OFF);
  float*  ot = (float*)((char*)d_ws + OT_OFF);

  hipLaunchKernelGGL(prep_kernel, dim3(4 * kN + 4 + 1024), dim3(256), 0, stream,
                     x, W_in, b_in, W_hid, b_hid, W_out, b_out, wt, wo, xk);

  dim3 grid((kB / 256) * kN);   // 8192 blocks; bid&127=node -> node fixed per CU
  hipLaunchKernelGGL(dnpu_kernel, grid, dim3(256), 0, stream,
                     xk, controls, wt, wo, ot);

  hipLaunchKernelGGL(transpose_out, dim3(512), dim3(256), 0, stream, ot, out);
}